// Round 1
// baseline (801.345 us; speedup 1.0000x reference)
//
#include <hip/hip_runtime.h>
#include <math.h>

// ---------------------------------------------------------------------------
// Problem constants (fixed by reference): B=256, S=512, D=768, H1=128,
// topk=12, proj hidden=256, n_rows=5, n_cols=12.
// ---------------------------------------------------------------------------
#define B_BATCH 256
#define S_LEN   512
#define D_DIM   768
#define H_ATT   128
#define TOPK    12
#define H_PROJ  256
#define N_ROWS  5
#define N_COLS  12

// ===========================================================================
// Kernel 1: fused  scores = tanh(X @ W1^T + b1) @ w2   (fp32, exact)
//   X: [M=131072, 768], W1: [128, 768], scores: [M]
// 128x128 block tile, BK=16, 8x8 register tile per thread (256 threads).
// att_b2 omitted: constant shift, irrelevant for top-k ordering.
// ===========================================================================
#define BM 128
#define BK 16

__global__ __launch_bounds__(256) void score_kernel(
    const float* __restrict__ th,   // [M, 768]
    const float* __restrict__ w1,   // [128, 768]
    const float* __restrict__ b1,   // [128]
    const float* __restrict__ w2,   // [128]
    float* __restrict__ scores)     // [M]
{
    __shared__ float As[BK][BM + 4];    // [k][m], +4 pad keeps 16B align
    __shared__ float Bs[BK][H_ATT + 4]; // [k][j]
    __shared__ float red[BM][17];       // token-score partial reduction

    const int tid   = threadIdx.x;
    const int m_blk = blockIdx.x * BM;
    const int tm = tid >> 4;          // 0..15
    const int tn = tid & 15;          // 0..15
    const int m0 = tm * 8;
    const int j0 = tn * 8;

    float acc[8][8];
#pragma unroll
    for (int i = 0; i < 8; ++i)
#pragma unroll
        for (int j = 0; j < 8; ++j) acc[i][j] = 0.0f;

    for (int k0 = 0; k0 < D_DIM; k0 += BK) {
        // Stage A tile: 128 rows x 16 k = 512 float4, 2 per thread.
#pragma unroll
        for (int i = 0; i < 2; ++i) {
            int f   = tid * 2 + i;
            int row = f >> 2;        // 0..127
            int c4  = f & 3;         // which float4 within the 16-wide k tile
            float4 v = *(const float4*)(th + (size_t)(m_blk + row) * D_DIM + k0 + c4 * 4);
            int kk = c4 * 4;
            As[kk + 0][row] = v.x; As[kk + 1][row] = v.y;
            As[kk + 2][row] = v.z; As[kk + 3][row] = v.w;
        }
        // Stage B tile (w1): 128 rows x 16 k, transposed into [k][j].
#pragma unroll
        for (int i = 0; i < 2; ++i) {
            int f   = tid * 2 + i;
            int row = f >> 2;
            int c4  = f & 3;
            float4 v = *(const float4*)(w1 + (size_t)row * D_DIM + k0 + c4 * 4);
            int kk = c4 * 4;
            Bs[kk + 0][row] = v.x; Bs[kk + 1][row] = v.y;
            Bs[kk + 2][row] = v.z; Bs[kk + 3][row] = v.w;
        }
        __syncthreads();

#pragma unroll
        for (int k = 0; k < BK; ++k) {
            float a[8], b[8];
            *(float4*)&a[0] = *(const float4*)&As[k][m0];
            *(float4*)&a[4] = *(const float4*)&As[k][m0 + 4];
            *(float4*)&b[0] = *(const float4*)&Bs[k][j0];
            *(float4*)&b[4] = *(const float4*)&Bs[k][j0 + 4];
#pragma unroll
            for (int i = 0; i < 8; ++i)
#pragma unroll
                for (int j = 0; j < 8; ++j) acc[i][j] += a[i] * b[j];
        }
        __syncthreads();
    }

    // Epilogue: tanh(pre + b1) * w2, partial-sum over this thread's 8 j's.
    float b1r[8], w2r[8];
#pragma unroll
    for (int j = 0; j < 8; ++j) { b1r[j] = b1[j0 + j]; w2r[j] = w2[j0 + j]; }

#pragma unroll
    for (int i = 0; i < 8; ++i) {
        float s = 0.0f;
#pragma unroll
        for (int j = 0; j < 8; ++j) s += tanhf(acc[i][j] + b1r[j]) * w2r[j];
        red[m0 + i][tn] = s;
    }
    __syncthreads();

    if (tid < BM) {
        float s = 0.0f;
#pragma unroll
        for (int t = 0; t < 16; ++t) s += red[tid][t];
        scores[m_blk + tid] = s;
    }
}

// ===========================================================================
// Kernel 2: per batch — mask, top-12 (tie -> smallest index, matching
// jax.lax.top_k), sort ascending, gather tokens, projector (exact GELU),
// [5,12] LayerNorm. One 256-thread block per batch.
// ===========================================================================
__global__ __launch_bounds__(256) void select_project_kernel(
    const float* __restrict__ th,      // [B*S, 768]
    const int*   __restrict__ mask,    // [B*S]
    const float* __restrict__ scores,  // [B*S]
    const float* __restrict__ pw1,     // [256, 768]
    const float* __restrict__ pb1,     // [256]
    const float* __restrict__ pw2,     // [5, 256]
    const float* __restrict__ pb2,     // [5]
    const float* __restrict__ gamma,   // [60]
    const float* __restrict__ beta,    // [60]
    float* __restrict__ out)           // [B, 5, 12]
{
    const int b   = blockIdx.x;
    const int tid = threadIdx.x;

    __shared__ float sc[S_LEN];
    __shared__ int   sel[TOPK];
    __shared__ float xsel[TOPK][D_DIM];
    __shared__ float gbuf[TOPK][H_PROJ + 1];
    __shared__ float rv[256];
    __shared__ int   ri[256];
    __shared__ float feat[N_ROWS * N_COLS];
    __shared__ float stats[2];

    const float NEG_MIN = -3.402823466e38f;  // finfo(float32).min

    for (int i = tid; i < S_LEN; i += 256) {
        float s = scores[(size_t)b * S_LEN + i];
        sc[i] = (mask[(size_t)b * S_LEN + i] == 0) ? NEG_MIN : s;
    }
    __syncthreads();

    // --- iterative top-12, tie-break to smallest index ---
    for (int it = 0; it < TOPK; ++it) {
        float best = -INFINITY; int bi = 1 << 30;
        for (int i = tid; i < S_LEN; i += 256) {
            float v = sc[i];
            if (v > best || (v == best && i < bi)) { best = v; bi = i; }
        }
        rv[tid] = best; ri[tid] = bi;
        __syncthreads();
        for (int s = 128; s > 0; s >>= 1) {
            if (tid < s) {
                float ov = rv[tid + s]; int oi = ri[tid + s];
                if (ov > rv[tid] || (ov == rv[tid] && oi < ri[tid])) {
                    rv[tid] = ov; ri[tid] = oi;
                }
            }
            __syncthreads();
        }
        if (tid == 0) { sel[it] = ri[0]; sc[ri[0]] = -INFINITY; }
        __syncthreads();
    }

    // sort selected indices ascending (preserve token order)
    if (tid == 0) {
        for (int i = 1; i < TOPK; ++i) {
            int k = sel[i], j = i - 1;
            while (j >= 0 && sel[j] > k) { sel[j + 1] = sel[j]; --j; }
            sel[j + 1] = k;
        }
    }
    __syncthreads();

    // --- gather selected tokens into LDS (float4) ---
    for (int f = tid; f < TOPK * (D_DIM / 4); f += 256) {
        int t = f / (D_DIM / 4);
        int c = f % (D_DIM / 4);
        ((float4*)xsel[t])[c] =
            ((const float4*)(th + ((size_t)b * S_LEN + sel[t]) * D_DIM))[c];
    }
    __syncthreads();

    // --- h = gelu(X_sel @ pw1^T + pb1): thread j owns column j ---
    {
        const int j = tid;
        float acc[TOPK];
        float bj = pb1[j];
#pragma unroll
        for (int t = 0; t < TOPK; ++t) acc[t] = bj;
        const float4* wrow = (const float4*)(pw1 + (size_t)j * D_DIM);
        for (int k4 = 0; k4 < D_DIM / 4; ++k4) {
            float4 w = wrow[k4];
#pragma unroll
            for (int t = 0; t < TOPK; ++t) {
                float4 x = ((const float4*)xsel[t])[k4];
                acc[t] += w.x * x.x + w.y * x.y + w.z * x.z + w.w * x.w;
            }
        }
#pragma unroll
        for (int t = 0; t < TOPK; ++t) {
            float h = acc[t];
            float g = 0.5f * h * (1.0f + erff(h * 0.70710678118654752f)); // exact GELU
            gbuf[t][j] = g;
        }
    }
    __syncthreads();

    // --- f @ pw2^T + pb2, write features[r][t] ---
    if (tid < TOPK * N_ROWS) {
        int t = tid / N_ROWS, r = tid % N_ROWS;
        float s = pb2[r];
        for (int j = 0; j < H_PROJ; ++j) s += gbuf[t][j] * pw2[r * H_PROJ + j];
        feat[r * N_COLS + t] = s;
    }
    __syncthreads();

    // --- LayerNorm over the 60 elements ---
    if (tid == 0) {
        float sum = 0.0f;
        for (int i = 0; i < N_ROWS * N_COLS; ++i) sum += feat[i];
        float mean = sum / (float)(N_ROWS * N_COLS);
        float sq = 0.0f;
        for (int i = 0; i < N_ROWS * N_COLS; ++i) {
            float d = feat[i] - mean; sq += d * d;
        }
        stats[0] = mean;
        stats[1] = sq / (float)(N_ROWS * N_COLS);
    }
    __syncthreads();

    if (tid < N_ROWS * N_COLS) {
        float x = feat[tid];
        float y = gamma[tid] * (x - stats[0]) * rsqrtf(stats[1] + 1e-5f) + beta[tid];
        out[(size_t)b * (N_ROWS * N_COLS) + tid] = y;
    }
}

// ===========================================================================
extern "C" void kernel_launch(void* const* d_in, const int* in_sizes, int n_in,
                              void* d_out, int out_size, void* d_ws, size_t ws_size,
                              hipStream_t stream) {
    const float* th    = (const float*)d_in[0];   // token_hidden [256,512,768]
    const int*   mask  = (const int*)  d_in[1];   // attention_mask [256,512]
    const float* aw1   = (const float*)d_in[2];   // att_w1 [128,768]
    const float* ab1   = (const float*)d_in[3];   // att_b1 [128]
    const float* aw2   = (const float*)d_in[4];   // att_w2 [1,128]
    // d_in[5] att_b2: constant shift, does not affect top-k ordering -> unused
    const float* pw1   = (const float*)d_in[6];   // proj_w1 [256,768]
    const float* pb1   = (const float*)d_in[7];   // proj_b1 [256]
    const float* pw2   = (const float*)d_in[8];   // proj_w2 [5,256]
    const float* pb2   = (const float*)d_in[9];   // proj_b2 [5]
    const float* gam   = (const float*)d_in[10];  // ln_gamma [5,12]
    const float* bet   = (const float*)d_in[11];  // ln_beta [5,12]
    float* out = (float*)d_out;

    float* scores = (float*)d_ws;  // [B*S] = 131072 floats = 512 KB

    const int M = B_BATCH * S_LEN;  // 131072
    hipLaunchKernelGGL(score_kernel, dim3(M / BM), dim3(256), 0, stream,
                       th, aw1, ab1, aw2, scores);
    hipLaunchKernelGGL(select_project_kernel, dim3(B_BATCH), dim3(256), 0, stream,
                       th, mask, scores, pw1, pb1, pw2, pb2, gam, bet, out);
}

// Round 2
// 767.702 us; speedup vs baseline: 1.0438x; 1.0438x over previous
//
#include <hip/hip_runtime.h>
#include <math.h>

// ---------------------------------------------------------------------------
// B=256, S=512, D=768, H_att=128, topk=12, proj hidden=256, rows=5, cols=12.
//
// Pipeline:
//   K0 prep: w1 -> split-bf16 (hi/lo) MFMA B-fragment layout; w1 -> w1q
//            (k-major float4 repack for coalesced rescore reads).
//   K1 score_mfma: approx scores = tanh(X W1^T + b1) w2 via 3-pass split-bf16
//            MFMA (err ~4e-6, exact enough for candidate top-16 containment).
//   K2 select: per batch: masked approx top-16 -> exact fp32 rescore of the 16
//            candidates -> exact top-12 (tie: smallest index) -> sort by index
//            -> fp32 projector (exact GELU) -> LayerNorm.
// ---------------------------------------------------------------------------
#define B_BATCH 256
#define S_LEN   512
#define D_DIM   768
#define H_ATT   128
#define TOPK    12
#define NCAND   16
#define H_PROJ  256
#define N_ROWS  5
#define N_COLS  12

typedef __bf16 bf16x4 __attribute__((ext_vector_type(4)));
typedef __bf16 bf16x8 __attribute__((ext_vector_type(8)));
typedef float  f32x4  __attribute__((ext_vector_type(4)));

// ws layout (bytes):
//   [0, 524288)        approx scores, 131072 f32
//   [524288, 720896)   w1 hi bf16 frags: [(nt*24+kt)*64+lane]*8+j  (98304 bf16)
//   [720896, 917504)   w1 lo bf16 frags (same layout)
//   [917504, 1310720)  w1q: float4[k4*128+n] = w1[n][4k4..4k4+3]   (98304 f32)
#define WS_SCORES 0
#define WS_WHI    524288
#define WS_WLO    720896
#define WS_W1Q    917504

// ===========================================================================
// K0: prep (768 blocks x 256 threads, one element each)
// ===========================================================================
__global__ __launch_bounds__(256) void prep_kernel(
    const float* __restrict__ w1, __bf16* __restrict__ whi,
    __bf16* __restrict__ wlo, float* __restrict__ w1q)
{
    int id = blockIdx.x * 256 + threadIdx.x;
    if (id < 98304) {
        // split-bf16 B-fragment build: flat id = ((nt*24+kt)*64+lane)*8+j
        int j    = id & 7;
        int lane = (id >> 3) & 63;
        int rest = id >> 9;            // 0..191
        int kt   = rest % 24;
        int nt   = rest / 24;
        int n = nt * 16 + (lane & 15);
        int k = kt * 32 + (lane >> 4) * 8 + j;
        float f = w1[n * D_DIM + k];
        __bf16 h = (__bf16)f;
        whi[id] = h;
        wlo[id] = (__bf16)(f - (float)h);
    } else {
        // w1q repack: flat e2 = (k4*128+n)*4+i
        int e2 = id - 98304;
        int i  = e2 & 3;
        int n  = (e2 >> 2) & 127;
        int k4 = e2 >> 9;
        w1q[e2] = w1[n * D_DIM + k4 * 4 + i];
    }
}

// ===========================================================================
// K1: approx scores via 3-pass split-bf16 MFMA (1024 blocks x 256 threads)
//     block tile M=128 (4 waves x 2 m-tiles), N=128 (8 n-tiles), K=768 (24 kt)
// ===========================================================================
__global__ __launch_bounds__(256, 3) void score_mfma(
    const float*  __restrict__ th,    // [M=131072, 768]
    const __bf16* __restrict__ whi,   // B-frags hi
    const __bf16* __restrict__ wlo,   // B-frags lo
    const float*  __restrict__ b1,    // [128]
    const float*  __restrict__ w2,    // [128]
    float* __restrict__ scores)       // [M]
{
    __shared__ __bf16 Ah[8 * 512];   // 8 m-tiles x 64 lanes x 8 bf16 = 8KB
    __shared__ __bf16 Al[8 * 512];
    __shared__ __bf16 Bh[8 * 512];   // 8 n-tiles x 64 lanes x 8 bf16 = 8KB
    __shared__ __bf16 Bl[8 * 512];

    const int tid = threadIdx.x;
    const int wv  = tid >> 6;
    const int ln  = tid & 63;
    const int mblk = blockIdx.x * 128;

    f32x4 acc[2][8];
    const f32x4 z = {0.f, 0.f, 0.f, 0.f};
#pragma unroll
    for (int i = 0; i < 2; ++i)
#pragma unroll
        for (int j = 0; j < 8; ++j) acc[i][j] = z;

    for (int kt = 0; kt < 24; ++kt) {
        // ---- issue global loads (A fp32 tile + pre-swizzled B frags) ----
        float4 v[4];
#pragma unroll
        for (int i = 0; i < 4; ++i) {
            int f = tid + 256 * i;       // 0..1023
            int row = f >> 3, q = f & 7; // row 0..127, q = float4 slot in 32-k
            v[i] = *(const float4*)(th + (size_t)(mblk + row) * D_DIM + kt * 32 + q * 4);
        }
        uint4 bb[4];
#pragma unroll
        for (int i = 0; i < 4; ++i) {
            int f = tid + 256 * i;
            int r = f & 511;
            int nt = r >> 6, l = r & 63;
            const __bf16* src = (f >> 9) ? wlo : whi;
            bb[i] = *(const uint4*)(src + ((size_t)(nt * 24 + kt) * 64 + l) * 8);
        }
        __syncthreads();   // previous iteration's LDS reads done

        // ---- stage A (convert + split) into XOR-swizzled fragment layout ----
#pragma unroll
        for (int i = 0; i < 4; ++i) {
            int f = tid + 256 * i;
            int row = f >> 3, q = f & 7;
            int mt = row >> 4, kq = q >> 1;
            int l16 = (row & 15) | (kq << 4);
            int a16 = l16 ^ (kq << 2);       // break 4-way write conflict
            __bf16 h0 = (__bf16)v[i].x, h1 = (__bf16)v[i].y;
            __bf16 h2 = (__bf16)v[i].z, h3 = (__bf16)v[i].w;
            bf16x4 hv = {h0, h1, h2, h3};
            bf16x4 lv = {(__bf16)(v[i].x - (float)h0), (__bf16)(v[i].y - (float)h1),
                         (__bf16)(v[i].z - (float)h2), (__bf16)(v[i].w - (float)h3)};
            int off = mt * 512 + a16 * 8 + (q & 1) * 4;
            *(bf16x4*)(&Ah[off]) = hv;
            *(bf16x4*)(&Al[off]) = lv;
        }
        // ---- stage B frags (verbatim copy) ----
#pragma unroll
        for (int i = 0; i < 4; ++i) {
            int f = tid + 256 * i;
            int r = f & 511;
            int nt = r >> 6, l = r & 63;
            __bf16* dst = (f >> 9) ? Bl : Bh;
            *(uint4*)(&dst[nt * 512 + l * 8]) = bb[i];
        }
        __syncthreads();

        // ---- MFMA: 3-pass split accumulate ----
        const int al = ln ^ (((ln >> 4) & 3) << 2);
        bf16x8 ah0 = *(bf16x8*)(&Ah[(wv * 2 + 0) * 512 + al * 8]);
        bf16x8 ah1 = *(bf16x8*)(&Ah[(wv * 2 + 1) * 512 + al * 8]);
        bf16x8 al0 = *(bf16x8*)(&Al[(wv * 2 + 0) * 512 + al * 8]);
        bf16x8 al1 = *(bf16x8*)(&Al[(wv * 2 + 1) * 512 + al * 8]);
#pragma unroll
        for (int nt = 0; nt < 8; ++nt) {
            bf16x8 bh = *(bf16x8*)(&Bh[nt * 512 + ln * 8]);
            bf16x8 bl = *(bf16x8*)(&Bl[nt * 512 + ln * 8]);
            acc[0][nt] = __builtin_amdgcn_mfma_f32_16x16x32_bf16(ah0, bh, acc[0][nt], 0, 0, 0);
            acc[0][nt] = __builtin_amdgcn_mfma_f32_16x16x32_bf16(ah0, bl, acc[0][nt], 0, 0, 0);
            acc[0][nt] = __builtin_amdgcn_mfma_f32_16x16x32_bf16(al0, bh, acc[0][nt], 0, 0, 0);
            acc[1][nt] = __builtin_amdgcn_mfma_f32_16x16x32_bf16(ah1, bh, acc[1][nt], 0, 0, 0);
            acc[1][nt] = __builtin_amdgcn_mfma_f32_16x16x32_bf16(ah1, bl, acc[1][nt], 0, 0, 0);
            acc[1][nt] = __builtin_amdgcn_mfma_f32_16x16x32_bf16(al1, bh, acc[1][nt], 0, 0, 0);
        }
    }

    // ---- epilogue: s = sum_n tanh(pre + b1[n]) * w2[n]; reduce over 16 cols ----
    const int col = ln & 15;
    float b1v[8], w2v[8];
#pragma unroll
    for (int nt = 0; nt < 8; ++nt) {
        b1v[nt] = b1[nt * 16 + col];
        w2v[nt] = w2[nt * 16 + col];
    }
#pragma unroll
    for (int mf = 0; mf < 2; ++mf)
#pragma unroll
        for (int r = 0; r < 4; ++r) {
            float s = 0.f;
#pragma unroll
            for (int nt = 0; nt < 8; ++nt)
                s += tanhf(acc[mf][nt][r] + b1v[nt]) * w2v[nt];
            s += __shfl_xor(s, 1, 64);
            s += __shfl_xor(s, 2, 64);
            s += __shfl_xor(s, 4, 64);
            s += __shfl_xor(s, 8, 64);
            if (col == 0)
                scores[mblk + wv * 32 + mf * 16 + (ln >> 4) * 4 + r] = s;
        }
}

// ===========================================================================
// K2: per batch — masked approx top-16, exact fp32 rescore, top-12, sort,
//     projector (exact GELU), LayerNorm. 256 blocks x 256 threads.
// ===========================================================================
__global__ __launch_bounds__(256) void select_kernel(
    const float* __restrict__ th,      // [B*S, 768]
    const int*   __restrict__ mask,    // [B*S]
    const float* __restrict__ ascores, // approx scores [B*S]
    const float* __restrict__ w1q,     // [192*128] float4-packed att_w1
    const float* __restrict__ ab1,     // att_b1 [128]
    const float* __restrict__ aw2,     // att_w2 [128]
    const float* __restrict__ pw1,     // [256, 768]
    const float* __restrict__ pb1,     // [256]
    const float* __restrict__ pw2,     // [5, 256]
    const float* __restrict__ pb2,     // [5]
    const float* __restrict__ gamma,   // [60]
    const float* __restrict__ beta,    // [60]
    float* __restrict__ out)           // [B, 5, 12]
{
    const int b   = blockIdx.x;
    const int tid = threadIdx.x;
    const int wv  = tid >> 6;
    const int ln  = tid & 63;

    __shared__ float4 xc[NCAND][192];        // 48KB candidate rows (fp32)
    __shared__ float sc[S_LEN];              // 2KB
    __shared__ unsigned long long wbest[4];
    __shared__ int   cand[NCAND];
    __shared__ float redW[4][8];
    __shared__ float exact_sc[NCAND];
    __shared__ int   sel_slot[TOPK];
    __shared__ float gbuf[TOPK][H_PROJ + 1]; // 12.3KB
    __shared__ float feat[N_ROWS * N_COLS];
    __shared__ float stats[2];

    const float NEG_MIN = -3.402823466e38f;

    for (int i = tid; i < S_LEN; i += 256) {
        float s = ascores[(size_t)b * S_LEN + i];
        sc[i] = (mask[(size_t)b * S_LEN + i] == 0) ? NEG_MIN : s;
    }
    __syncthreads();

    // --- approx top-16 (order-preserving key pack, tie -> smallest index) ---
    for (int it = 0; it < NCAND; ++it) {
        float v0 = sc[tid], v1 = sc[tid + 256];
        unsigned k0 = __float_as_uint(v0);
        k0 = ((int)k0 >= 0) ? (k0 | 0x80000000u) : ~k0;
        unsigned k1 = __float_as_uint(v1);
        k1 = ((int)k1 >= 0) ? (k1 | 0x80000000u) : ~k1;
        unsigned long long p0 = ((unsigned long long)k0 << 32) | (0xFFFFFFFFu - (unsigned)tid);
        unsigned long long p1 = ((unsigned long long)k1 << 32) | (0xFFFFFFFFu - (unsigned)(tid + 256));
        unsigned long long best = p0 > p1 ? p0 : p1;
#pragma unroll
        for (int m = 1; m <= 32; m <<= 1) {
            unsigned long long o = __shfl_xor(best, m, 64);
            if (o > best) best = o;
        }
        if (ln == 0) wbest[wv] = best;
        __syncthreads();
        if (tid == 0) {
            unsigned long long bb = wbest[0];
            for (int w = 1; w < 4; ++w) if (wbest[w] > bb) bb = wbest[w];
            int idx = (int)(0xFFFFFFFFu - (unsigned)(bb & 0xFFFFFFFFu));
            cand[it] = idx;
            sc[idx] = -INFINITY;
        }
        __syncthreads();
    }

    // --- stage candidate rows into LDS (fp32, float4) ---
#pragma unroll
    for (int i = 0; i < 12; ++i) {
        int f = tid + 256 * i;           // 0..3071
        int c = f / 192, k4 = f % 192;
        xc[c][k4] = *(const float4*)(th + ((size_t)b * S_LEN + cand[c]) * D_DIM + k4 * 4);
    }
    __syncthreads();

    // --- exact fp32 rescore of 16 candidates ---
    {
        const int n = tid & 127;         // att hidden index
        const int h = tid >> 7;          // candidate parity
        float accs[8];
#pragma unroll
        for (int ci = 0; ci < 8; ++ci) accs[ci] = 0.f;
        for (int k4 = 0; k4 < 192; ++k4) {
            float4 w = *(const float4*)(w1q + (size_t)(k4 * 128 + n) * 4);
#pragma unroll
            for (int ci = 0; ci < 8; ++ci) {
                float4 x = xc[2 * ci + h][k4];
                accs[ci] += w.x * x.x + w.y * x.y + w.z * x.z + w.w * x.w;
            }
        }
        float b1n = ab1[n], w2n = aw2[n];
#pragma unroll
        for (int ci = 0; ci < 8; ++ci) {
            float val = tanhf(accs[ci] + b1n) * w2n;
            val += __shfl_xor(val, 1, 64);
            val += __shfl_xor(val, 2, 64);
            val += __shfl_xor(val, 4, 64);
            val += __shfl_xor(val, 8, 64);
            val += __shfl_xor(val, 16, 64);
            val += __shfl_xor(val, 32, 64);
            if (ln == 0) redW[wv][ci] = val;
        }
    }
    __syncthreads();
    if (tid < NCAND) {
        int c = tid;
        float ex = (c & 1) ? (redW[2][c >> 1] + redW[3][c >> 1])
                           : (redW[0][c >> 1] + redW[1][c >> 1]);
        if (mask[(size_t)b * S_LEN + cand[c]] == 0) ex = -INFINITY;
        exact_sc[c] = ex;
    }
    __syncthreads();

    // --- exact top-12 among candidates (tie -> smallest token index), sort ---
    if (tid == 0) {
        unsigned picked = 0;
        int slots[TOPK];
        for (int it = 0; it < TOPK; ++it) {
            float best = -INFINITY; int bslot = -1; int bidx = 1 << 30;
            for (int c = 0; c < NCAND; ++c) {
                if (picked & (1u << c)) continue;
                float e = exact_sc[c]; int idx = cand[c];
                if (e > best || (e == best && idx < bidx)) { best = e; bslot = c; bidx = idx; }
            }
            picked |= 1u << bslot;
            slots[it] = bslot;
        }
        // insertion sort by token index ascending
        for (int i = 1; i < TOPK; ++i) {
            int s = slots[i], key = cand[s], j = i - 1;
            while (j >= 0 && cand[slots[j]] > key) { slots[j + 1] = slots[j]; --j; }
            slots[j + 1] = s;
        }
        for (int t = 0; t < TOPK; ++t) sel_slot[t] = slots[t];
    }
    __syncthreads();

    // --- projector: h = gelu(X_sel @ pw1^T + pb1), thread j owns column j ---
    {
        const int j = tid;
        int slots[TOPK];
#pragma unroll
        for (int t = 0; t < TOPK; ++t) slots[t] = sel_slot[t];
        float accp[TOPK];
        float bj = pb1[j];
#pragma unroll
        for (int t = 0; t < TOPK; ++t) accp[t] = bj;
        const float4* wrow = (const float4*)(pw1 + (size_t)j * D_DIM);
        for (int k4 = 0; k4 < 192; ++k4) {
            float4 w = wrow[k4];
#pragma unroll
            for (int t = 0; t < TOPK; ++t) {
                float4 x = xc[slots[t]][k4];
                accp[t] += w.x * x.x + w.y * x.y + w.z * x.z + w.w * x.w;
            }
        }
#pragma unroll
        for (int t = 0; t < TOPK; ++t) {
            float hh = accp[t];
            gbuf[t][j] = 0.5f * hh * (1.0f + erff(hh * 0.70710678118654752f));
        }
    }
    __syncthreads();

    // --- f @ pw2^T + pb2 ---
    if (tid < TOPK * N_ROWS) {
        int t = tid / N_ROWS, r = tid % N_ROWS;
        float s = pb2[r];
        for (int j = 0; j < H_PROJ; ++j) s += gbuf[t][j] * pw2[r * H_PROJ + j];
        feat[r * N_COLS + t] = s;
    }
    __syncthreads();

    // --- LayerNorm over 60 elements ---
    if (tid == 0) {
        float sum = 0.f;
        for (int i = 0; i < N_ROWS * N_COLS; ++i) sum += feat[i];
        float mean = sum / 60.f;
        float sq = 0.f;
        for (int i = 0; i < N_ROWS * N_COLS; ++i) { float d = feat[i] - mean; sq += d * d; }
        stats[0] = mean;
        stats[1] = sq / 60.f;
    }
    __syncthreads();
    if (tid < N_ROWS * N_COLS) {
        float x = feat[tid];
        out[(size_t)b * 60 + tid] =
            gamma[tid] * (x - stats[0]) * rsqrtf(stats[1] + 1e-5f) + beta[tid];
    }
}

// ===========================================================================
extern "C" void kernel_launch(void* const* d_in, const int* in_sizes, int n_in,
                              void* d_out, int out_size, void* d_ws, size_t ws_size,
                              hipStream_t stream) {
    const float* th   = (const float*)d_in[0];
    const int*   mask = (const int*)  d_in[1];
    const float* aw1  = (const float*)d_in[2];
    const float* ab1  = (const float*)d_in[3];
    const float* aw2  = (const float*)d_in[4];
    // d_in[5] att_b2: constant shift — irrelevant for top-k ordering
    const float* pw1  = (const float*)d_in[6];
    const float* pb1  = (const float*)d_in[7];
    const float* pw2  = (const float*)d_in[8];
    const float* pb2  = (const float*)d_in[9];
    const float* gam  = (const float*)d_in[10];
    const float* bet  = (const float*)d_in[11];
    float* out = (float*)d_out;

    char* ws = (char*)d_ws;
    float*  scores = (float*)(ws + WS_SCORES);
    __bf16* whi    = (__bf16*)(ws + WS_WHI);
    __bf16* wlo    = (__bf16*)(ws + WS_WLO);
    float*  w1q    = (float*)(ws + WS_W1Q);

    hipLaunchKernelGGL(prep_kernel, dim3(768), dim3(256), 0, stream,
                       aw1, whi, wlo, w1q);
    hipLaunchKernelGGL(score_mfma, dim3(131072 / 128), dim3(256), 0, stream,
                       th, whi, wlo, ab1, aw2, scores);
    hipLaunchKernelGGL(select_kernel, dim3(B_BATCH), dim3(256), 0, stream,
                       th, mask, scores, w1q, ab1, aw2,
                       pw1, pb1, pw2, pb2, gam, bet, out);
}